// Round 5
// baseline (229.908 us; speedup 1.0000x reference)
//
#include <hip/hip_runtime.h>

// MACE symmetric contraction (corr-3), N=2048, NL=16, C=128, E=10, P3=23, P2=4, P1=1.
// out[n,c] = sum_{a<=b<=i} A3[t,tri,c] x_a x_b x_i + sum_{a<=b} A2[t,pr,c] x_a x_b
//          + sum_a A1[t,a,c] x_a,  with A3 = U3sym @ W3[t] etc. (t = atom type).
// R7: shrink per-thread state instead of fighting the allocator.
//   - GG=2 atoms/group: xv = 32 regs, live set ~60-70 (was 104 at GG=4, which
//     spilled at ANY cap: R4/R5/R6 all showed ~110MB scratch stores).
//   - 2 BALANCED slices split at a=4 (452 tris+lin vs 364 tris+more pairs),
//     slice 2 only materializes x[4..16).
//   - sched_barrier removed: with ~60 headroom regs under a 128 cap, the
//     pressure-aware scheduler can pipeline ~15 float4 loads WITHOUT spilling.
//   - __launch_bounds__(128,4): VGPR cap 128, 16 waves/CU, grid ~8 blocks/CU.

constexpr int NL = 16;
constexpr int CC = 128;
constexpr int EE = 10;
constexpr int P3 = 23;
constexpr int P2 = 4;
constexpr int P1 = 1;
constexpr int NTRI = 816;   // C(18,3): a<=b<=i from 16
constexpr int NPAIR = 136;  // C(17,2): a<=b from 16
constexpr int GG = 2;       // atoms per group
constexpr int SPLIT = 4;    // nest split: a in [0,4) | [4,16)

constexpr int pairsBefore(int a) {
    int s = 0;
    for (int x = 0; x < a; x++) s += NL - x;
    return s;
}
constexpr int trisBefore(int a) {
    int s = 0;
    for (int x = 0; x < a; x++) s += (NL - x) * (NL - x + 1) / 2;
    return s;
}
static_assert(trisBefore(SPLIT) % 4 == 0, "tri split must be float4-aligned");
static_assert(pairsBefore(SPLIT) % 2 == 0, "pair split must be float2-aligned");

// ---------------- Precompute: symmetrized U tensors ----------------
__global__ void k_symU(const float* __restrict__ U3, const float* __restrict__ U2,
                       float* __restrict__ U3s, float* __restrict__ U2s) {
    int idx = blockIdx.x * blockDim.x + threadIdx.x;
    if (idx < NTRI * P3) {
        int tri = idx / P3, k = idx % P3;
        int rem = tri, a = 0;
        while (rem >= (NL - a) * (NL - a + 1) / 2) { rem -= (NL - a) * (NL - a + 1) / 2; a++; }
        int b = a;
        while (rem >= NL - b) { rem -= NL - b; b++; }
        int i = b + rem;
        auto u = [&](int p, int q, int r) { return U3[((p * NL + q) * NL + r) * P3 + k]; };
        float s = u(a,b,i) + u(a,i,b) + u(b,a,i) + u(b,i,a) + u(i,a,b) + u(i,b,a);
        int m = (a == b && b == i) ? 6 : ((a == b || b == i) ? 2 : 1);
        U3s[idx] = s / (float)m;
    } else if (idx < NTRI * P3 + NPAIR * P2) {
        int j = idx - NTRI * P3;
        int pr = j / P2, k = j % P2;
        int rem = pr, a = 0;
        while (rem >= NL - a) { rem -= NL - a; a++; }
        int b = a + rem;
        float s = U2[(a * NL + b) * P2 + k];
        if (a != b) s += U2[(b * NL + a) * P2 + k];
        U2s[pr * P2 + k] = s;
    }
}

// ---------------- Precompute: per-type coefficient tables (interleaved) -------
// A3 layout: [t][tri/4][c][4]  -> thread c reads float4 of 4 consecutive tri
// A2 layout: [t][pr/2][c][2]   -> float2 of 2 consecutive pairs
// A1 layout: [t][a][c]         -> scalar
__global__ void k_buildA(const float* __restrict__ U3s, const float* __restrict__ U2s,
                         const float* __restrict__ U1,
                         const float* __restrict__ W3, const float* __restrict__ W2,
                         const float* __restrict__ W1,
                         float* __restrict__ A3, float* __restrict__ A2, float* __restrict__ A1) {
    constexpr int NB3 = EE * (NTRI / 4);
    constexpr int NB2 = EE * (NPAIR / 2);
    int b = blockIdx.x;
    int c = threadIdx.x;  // 128 threads = channels
    if (b < NB3) {
        int t = b / (NTRI / 4), tri4 = b % (NTRI / 4);
        float4 sv = {0.f, 0.f, 0.f, 0.f};
        #pragma unroll
        for (int k = 0; k < P3; k++) {
            float w = W3[(t * P3 + k) * CC + c];
            sv.x += U3s[(tri4 * 4 + 0) * P3 + k] * w;
            sv.y += U3s[(tri4 * 4 + 1) * P3 + k] * w;
            sv.z += U3s[(tri4 * 4 + 2) * P3 + k] * w;
            sv.w += U3s[(tri4 * 4 + 3) * P3 + k] * w;
        }
        ((float4*)A3)[((size_t)t * (NTRI / 4) + tri4) * CC + c] = sv;
    } else if (b < NB3 + NB2) {
        int j = b - NB3;
        int t = j / (NPAIR / 2), pr2 = j % (NPAIR / 2);
        float2 sv = {0.f, 0.f};
        #pragma unroll
        for (int k = 0; k < P2; k++) {
            float w = W2[(t * P2 + k) * CC + c];
            sv.x += U2s[(pr2 * 2 + 0) * P2 + k] * w;
            sv.y += U2s[(pr2 * 2 + 1) * P2 + k] * w;
        }
        ((float2*)A2)[((size_t)t * (NPAIR / 2) + pr2) * CC + c] = sv;
    } else {
        int t = b - NB3 - NB2;
        #pragma unroll
        for (int a = 0; a < NL; a++) {
            float s = 0.f;
            #pragma unroll
            for (int k = 0; k < P1; k++) s += U1[a * P1 + k] * W1[(t * P1 + k) * CC + c];
            A1[((size_t)t * NL + a) * CC + c] = s;
        }
    }
}

// ---------------- Atom bucketing by type: ONE single-block kernel ----------
__global__ void k_prep(const int* __restrict__ types, int* __restrict__ buckets,
                       int* __restrict__ groups, int* __restrict__ ngroups, int N) {
    __shared__ int scnt[EE];
    __shared__ int goff[EE + 1];
    int tid = threadIdx.x;
    if (tid < EE) scnt[tid] = 0;
    __syncthreads();
    for (int n = tid; n < N; n += blockDim.x) {
        int t = types[n];
        int pos = atomicAdd(&scnt[t], 1);
        buckets[t * N + pos] = n;
    }
    __syncthreads();
    if (tid == 0) {
        int off = 0;
        for (int t = 0; t < EE; t++) { goff[t] = off; off += (scnt[t] + GG - 1) / GG; }
        goff[EE] = off;
        *ngroups = off;
    }
    __syncthreads();
    for (int t = 0; t < EE; t++) {
        int cnt = scnt[t];
        int ng = (cnt + GG - 1) / GG;
        for (int g = tid; g < ng; g += blockDim.x) {
            int* gr = &groups[(goff[t] + g) * 4];
            int nv = cnt - g * GG; if (nv > GG) nv = GG;
            gr[0] = t;
            gr[3] = nv;
            for (int j = 0; j < GG; j++) {
                int jj = j < nv ? j : nv - 1;
                gr[1 + j] = buckets[t * N + g * GG + jj];
            }
        }
    }
}

// ---------------- Main: cubic form per (group-slice, channel) ----------------
// Per (a,b): p = x_a*x_b; s accumulates sum_i w3*x_i over i in [b,NL);
// epilogue acc += p*(w2+s). One FMA per cubic monomial. Slice only
// materializes x[A0..NL) (compile-time extent -> all-register).
template <int A0, int A1e, bool LIN>
__device__ __forceinline__ void run_slice(const float* __restrict__ x,
                                          const float4* __restrict__ a3v,
                                          const float2* __restrict__ a2v,
                                          const float* __restrict__ a1p,
                                          const int (&na)[GG], int nvalid, int c,
                                          float* __restrict__ out) {
    constexpr int NX = NL - A0;
    float xv[GG][NX];
    #pragma unroll
    for (int g = 0; g < GG; g++)
        #pragma unroll
        for (int i = 0; i < NX; i++)
            xv[g][i] = x[((size_t)na[g] * NL + A0 + i) * CC + c];

    float acc[GG];
    #pragma unroll
    for (int g = 0; g < GG; g++) acc[g] = 0.f;

    if (LIN) {
        static_assert(!LIN || A0 == 0, "linear term needs full x range");
        #pragma unroll
        for (int a = 0; a < NL; a++) {
            float w = a1p[a * CC];
            #pragma unroll
            for (int g = 0; g < GG; g++) acc[g] += w * xv[g][a - A0];
        }
    }

    float4 w4 = {0.f, 0.f, 0.f, 0.f};
    float2 wp = {0.f, 0.f};
    int tri = trisBefore(A0), pr = pairsBefore(A0);
    #pragma unroll
    for (int a = A0; a < A1e; a++) {
        #pragma unroll
        for (int b = a; b < NL; b++) {
            float p[GG], s[GG];
            #pragma unroll
            for (int g = 0; g < GG; g++) p[g] = xv[g][a - A0] * xv[g][b - A0];
            #pragma unroll
            for (int i = b; i < NL; i++) {
                if ((tri & 3) == 0) w4 = a3v[(size_t)(tri >> 2) * CC];
                int r = tri & 3;
                float w3 = (r == 0) ? w4.x : (r == 1) ? w4.y : (r == 2) ? w4.z : w4.w;
                tri++;
                if (i == b) {
                    #pragma unroll
                    for (int g = 0; g < GG; g++) s[g] = w3 * xv[g][b - A0];
                } else {
                    #pragma unroll
                    for (int g = 0; g < GG; g++) s[g] += w3 * xv[g][i - A0];
                }
            }
            if ((pr & 1) == 0) wp = a2v[(size_t)(pr >> 1) * CC];
            float w2 = ((pr & 1) == 0) ? wp.x : wp.y;
            pr++;
            #pragma unroll
            for (int g = 0; g < GG; g++) acc[g] += p[g] * (w2 + s[g]);
        }
    }

    #pragma unroll
    for (int g = 0; g < GG; g++)
        if (g < nvalid) atomicAdd(&out[(size_t)na[g] * CC + c], acc[g]);
}

// __launch_bounds__(128, 4): 4 waves/EU -> VGPR cap 128. Live set ~60-70 at
// GG=2, leaving ~60 regs of headroom for the scheduler to pipeline loads.
__global__ __launch_bounds__(CC, 4) void k_main(const float* __restrict__ x,
                                                const float* __restrict__ A3,
                                                const float* __restrict__ A2,
                                                const float* __restrict__ A1,
                                                const int* __restrict__ groups,
                                                const int* __restrict__ ngroups,
                                                float* __restrict__ out) {
    // XCD-chunked bijective swizzle (m204 form): each XCD gets a contiguous
    // LOGICAL group chunk so its L2 holds the A3 slices of ~1-2 atom types.
    int pb = blockIdx.x;
    int nb = gridDim.x;
    int q = nb >> 3, r = nb & 7;
    int xcd = pb & 7, sub = pb >> 3;
    int blk = (xcd < r ? xcd * (q + 1) : r * (q + 1) + (xcd - r) * q) + sub;
    if (blk >= *ngroups) return;
    const int* gr = groups + blk * 4;
    int t = gr[0];
    int nvalid = gr[3];
    int c = threadIdx.x;

    int na[GG];
    #pragma unroll
    for (int g = 0; g < GG; g++) na[g] = gr[1 + g];

    const float4* a3v = (const float4*)A3 + (size_t)t * (NTRI / 4) * CC + c;
    const float2* a2v = (const float2*)A2 + (size_t)t * (NPAIR / 2) * CC + c;
    const float* a1p = A1 + (size_t)t * NL * CC + c;

    if (blockIdx.y == 0)
        run_slice<0, SPLIT, true>(x, a3v, a2v, a1p, na, nvalid, c, out);
    else
        run_slice<SPLIT, NL, false>(x, a3v, a2v, a1p, na, nvalid, c, out);
}

extern "C" void kernel_launch(void* const* d_in, const int* in_sizes, int n_in,
                              void* d_out, int out_size, void* d_ws, size_t ws_size,
                              hipStream_t stream) {
    const float* x   = (const float*)d_in[0];
    const int* types = (const int*)d_in[1];
    const float* U3  = (const float*)d_in[2];
    const float* U2  = (const float*)d_in[3];
    const float* U1  = (const float*)d_in[4];
    const float* W3  = (const float*)d_in[5];
    const float* W2  = (const float*)d_in[6];
    const float* W1  = (const float*)d_in[7];
    float* out = (float*)d_out;
    int N = in_sizes[1];  // atom count (2048)

    int ngmax = (N + GG - 1) / GG + EE;  // strict upper bound on group count

    float* ws   = (float*)d_ws;
    float* U3s  = ws;                           // NTRI*P3
    float* U2s  = U3s + NTRI * P3;              // NPAIR*P2
    float* A3   = U2s + NPAIR * P2;             // EE*NTRI*CC (interleaved x4)
    float* A2   = A3 + (size_t)EE * NTRI * CC;  // EE*NPAIR*CC (interleaved x2)
    float* A1   = A2 + (size_t)EE * NPAIR * CC; // EE*NL*CC
    int* buckets = (int*)(A1 + (size_t)EE * NL * CC);  // EE*N
    int* groups  = buckets + (size_t)EE * N;    // ngmax*4
    int* ngroups = groups + (size_t)ngmax * 4;

    hipMemsetAsync(out, 0, (size_t)out_size * sizeof(float), stream);

    int symThreads = NTRI * P3 + NPAIR * P2;
    hipLaunchKernelGGL(k_symU, dim3((symThreads + 255) / 256), dim3(256), 0, stream,
                       U3, U2, U3s, U2s);
    hipLaunchKernelGGL(k_buildA, dim3(EE * (NTRI / 4) + EE * (NPAIR / 2) + EE), dim3(CC), 0,
                       stream, U3s, U2s, U1, W3, W2, W1, A3, A2, A1);
    hipLaunchKernelGGL(k_prep, dim3(1), dim3(256), 0, stream,
                       types, buckets, groups, ngroups, N);
    hipLaunchKernelGGL(k_main, dim3(ngmax, 2), dim3(CC), 0, stream,
                       x, A3, A2, A1, groups, ngroups, out);
}

// Round 6
// 116.262 us; speedup vs baseline: 1.9775x; 1.9775x over previous
//
#include <hip/hip_runtime.h>

// MACE symmetric contraction (corr-3), N=2048, NL=16, C=128, E=10, P3=23, P2=4, P1=1.
// out[n,c] = sum_{a<=b<=i} A3[t,tri,c] x_a x_b x_i + sum_{a<=b} A2[t,pr,c] x_a x_b
//          + sum_a A1[t,a,c] x_a,  with A3 = U3sym @ W3[t] etc. (t = atom type).
// R8: RE-ANCHOR. The inherited R0 kernel had k_main <= 44us; every session
// variant (s[] running sum, XCD swizzle, 3-way split, GG=2) landed 136-147us
// with scratch-scale WRITE_SIZE. Restore R0's k_main EXACTLY (GG=4, 2-way
// split, (128,3), direct acc += w3*(p*x_i) body, no swizzle). Keep only the
// out-of-k_main wins: fused single-block k_prep, float4 k_buildA.

constexpr int NL = 16;
constexpr int CC = 128;
constexpr int EE = 10;
constexpr int P3 = 23;
constexpr int P2 = 4;
constexpr int P1 = 1;
constexpr int NTRI = 816;   // C(18,3): a<=b<=i from 16
constexpr int NPAIR = 136;  // C(17,2): a<=b from 16
constexpr int GG = 4;       // atoms per group
constexpr int ASPLIT = 4;   // nest split: a in [0,4) | [4,16)

constexpr int pairsBefore(int a) {
    int s = 0;
    for (int x = 0; x < a; x++) s += NL - x;
    return s;
}
constexpr int trisBefore(int a) {
    int s = 0;
    for (int x = 0; x < a; x++) s += (NL - x) * (NL - x + 1) / 2;
    return s;
}
static_assert(trisBefore(ASPLIT) % 4 == 0, "tri split must be float4-aligned");
static_assert(pairsBefore(ASPLIT) % 2 == 0, "pair split must be float2-aligned");

// ---------------- Precompute: symmetrized U tensors ----------------
__global__ void k_symU(const float* __restrict__ U3, const float* __restrict__ U2,
                       float* __restrict__ U3s, float* __restrict__ U2s) {
    int idx = blockIdx.x * blockDim.x + threadIdx.x;
    if (idx < NTRI * P3) {
        int tri = idx / P3, k = idx % P3;
        int rem = tri, a = 0;
        while (rem >= (NL - a) * (NL - a + 1) / 2) { rem -= (NL - a) * (NL - a + 1) / 2; a++; }
        int b = a;
        while (rem >= NL - b) { rem -= NL - b; b++; }
        int i = b + rem;
        auto u = [&](int p, int q, int r) { return U3[((p * NL + q) * NL + r) * P3 + k]; };
        float s = u(a,b,i) + u(a,i,b) + u(b,a,i) + u(b,i,a) + u(i,a,b) + u(i,b,a);
        int m = (a == b && b == i) ? 6 : ((a == b || b == i) ? 2 : 1);
        U3s[idx] = s / (float)m;
    } else if (idx < NTRI * P3 + NPAIR * P2) {
        int j = idx - NTRI * P3;
        int pr = j / P2, k = j % P2;
        int rem = pr, a = 0;
        while (rem >= NL - a) { rem -= NL - a; a++; }
        int b = a + rem;
        float s = U2[(a * NL + b) * P2 + k];
        if (a != b) s += U2[(b * NL + a) * P2 + k];
        U2s[pr * P2 + k] = s;
    }
}

// ---------------- Precompute: per-type coefficient tables (interleaved) -------
// A3 layout: [t][tri/4][c][4]  -> thread c reads float4 of 4 consecutive tri
// A2 layout: [t][pr/2][c][2]   -> float2 of 2 consecutive pairs
// A1 layout: [t][a][c]         -> scalar
__global__ void k_buildA(const float* __restrict__ U3s, const float* __restrict__ U2s,
                         const float* __restrict__ U1,
                         const float* __restrict__ W3, const float* __restrict__ W2,
                         const float* __restrict__ W1,
                         float* __restrict__ A3, float* __restrict__ A2, float* __restrict__ A1) {
    constexpr int NB3 = EE * (NTRI / 4);
    constexpr int NB2 = EE * (NPAIR / 2);
    int b = blockIdx.x;
    int c = threadIdx.x;  // 128 threads = channels
    if (b < NB3) {
        int t = b / (NTRI / 4), tri4 = b % (NTRI / 4);
        float4 sv = {0.f, 0.f, 0.f, 0.f};
        #pragma unroll
        for (int k = 0; k < P3; k++) {
            float w = W3[(t * P3 + k) * CC + c];
            sv.x += U3s[(tri4 * 4 + 0) * P3 + k] * w;
            sv.y += U3s[(tri4 * 4 + 1) * P3 + k] * w;
            sv.z += U3s[(tri4 * 4 + 2) * P3 + k] * w;
            sv.w += U3s[(tri4 * 4 + 3) * P3 + k] * w;
        }
        ((float4*)A3)[((size_t)t * (NTRI / 4) + tri4) * CC + c] = sv;
    } else if (b < NB3 + NB2) {
        int j = b - NB3;
        int t = j / (NPAIR / 2), pr2 = j % (NPAIR / 2);
        float2 sv = {0.f, 0.f};
        #pragma unroll
        for (int k = 0; k < P2; k++) {
            float w = W2[(t * P2 + k) * CC + c];
            sv.x += U2s[(pr2 * 2 + 0) * P2 + k] * w;
            sv.y += U2s[(pr2 * 2 + 1) * P2 + k] * w;
        }
        ((float2*)A2)[((size_t)t * (NPAIR / 2) + pr2) * CC + c] = sv;
    } else {
        int t = b - NB3 - NB2;
        #pragma unroll
        for (int a = 0; a < NL; a++) {
            float s = 0.f;
            #pragma unroll
            for (int k = 0; k < P1; k++) s += U1[a * P1 + k] * W1[(t * P1 + k) * CC + c];
            A1[((size_t)t * NL + a) * CC + c] = s;
        }
    }
}

// ---------------- Atom bucketing by type: ONE single-block kernel ----------
__global__ void k_prep(const int* __restrict__ types, int* __restrict__ buckets,
                       int* __restrict__ groups, int* __restrict__ ngroups, int N) {
    __shared__ int scnt[EE];
    __shared__ int goff[EE + 1];
    int tid = threadIdx.x;
    if (tid < EE) scnt[tid] = 0;
    __syncthreads();
    for (int n = tid; n < N; n += blockDim.x) {
        int t = types[n];
        int pos = atomicAdd(&scnt[t], 1);
        buckets[t * N + pos] = n;
    }
    __syncthreads();
    if (tid == 0) {
        int off = 0;
        for (int t = 0; t < EE; t++) { goff[t] = off; off += (scnt[t] + GG - 1) / GG; }
        goff[EE] = off;
        *ngroups = off;
    }
    __syncthreads();
    for (int t = 0; t < EE; t++) {
        int cnt = scnt[t];
        int ng = (cnt + GG - 1) / GG;
        for (int g = tid; g < ng; g += blockDim.x) {
            int* gr = &groups[(goff[t] + g) * 8];
            int nv = cnt - g * GG; if (nv > GG) nv = GG;
            gr[0] = t;
            gr[5] = nv;
            for (int j = 0; j < GG; j++) {
                int jj = j < nv ? j : nv - 1;
                gr[1 + j] = buckets[t * N + g * GG + jj];
            }
        }
    }
}

// ---------------- Main: evaluate cubic form per (group-half, channel) --------
// R0-exact body: per tri, acc[g] += w3 * (p[g] * xv[g][i]) — two independent
// FMA chains per g, no serial running sum.
template <int A0, int A1, bool LIN>
__device__ __forceinline__ void eval_nest(const float (&xv)[GG][NL],
                                          const float4* __restrict__ a3v,
                                          const float2* __restrict__ a2v,
                                          const float* __restrict__ a1p,
                                          float (&acc)[GG]) {
    if (LIN) {
        #pragma unroll
        for (int a = 0; a < NL; a++) {
            float w = a1p[a * CC];
            #pragma unroll
            for (int g = 0; g < GG; g++) acc[g] += w * xv[g][a];
        }
    }
    float4 w4 = {0.f, 0.f, 0.f, 0.f};
    float2 wp = {0.f, 0.f};
    int tri = trisBefore(A0), pr = pairsBefore(A0);
    #pragma unroll
    for (int a = A0; a < A1; a++) {
        #pragma unroll
        for (int b = a; b < NL; b++) {
            float p[GG];
            #pragma unroll
            for (int g = 0; g < GG; g++) p[g] = xv[g][a] * xv[g][b];
            if ((pr & 1) == 0) wp = a2v[(size_t)(pr >> 1) * CC];
            float w2 = ((pr & 1) == 0) ? wp.x : wp.y;
            pr++;
            #pragma unroll
            for (int g = 0; g < GG; g++) acc[g] += w2 * p[g];
            #pragma unroll
            for (int i = b; i < NL; i++) {
                if ((tri & 3) == 0) w4 = a3v[(size_t)(tri >> 2) * CC];
                int r = tri & 3;
                float w3 = (r == 0) ? w4.x : (r == 1) ? w4.y : (r == 2) ? w4.z : w4.w;
                tri++;
                #pragma unroll
                for (int g = 0; g < GG; g++) acc[g] += w3 * (p[g] * xv[g][i]);
            }
        }
    }
}

__global__ __launch_bounds__(CC, 3) void k_main(const float* __restrict__ x,
                                                const float* __restrict__ A3,
                                                const float* __restrict__ A2,
                                                const float* __restrict__ A1,
                                                const int* __restrict__ groups,
                                                const int* __restrict__ ngroups,
                                                float* __restrict__ out) {
    int blk = blockIdx.x;
    if (blk >= *ngroups) return;
    const int* gr = groups + blk * 8;
    int t = gr[0];
    int nvalid = gr[5];
    int c = threadIdx.x;

    int na[GG];
    #pragma unroll
    for (int g = 0; g < GG; g++) na[g] = gr[1 + g];

    float xv[GG][NL];
    #pragma unroll
    for (int g = 0; g < GG; g++)
        #pragma unroll
        for (int i = 0; i < NL; i++)
            xv[g][i] = x[((size_t)na[g] * NL + i) * CC + c];

    const float4* a3v = (const float4*)A3 + (size_t)t * (NTRI / 4) * CC + c;
    const float2* a2v = (const float2*)A2 + (size_t)t * (NPAIR / 2) * CC + c;
    const float* a1p = A1 + (size_t)t * NL * CC + c;

    float acc[GG] = {0.f, 0.f, 0.f, 0.f};
    if (blockIdx.y == 0)
        eval_nest<0, ASPLIT, true>(xv, a3v, a2v, a1p, acc);
    else
        eval_nest<ASPLIT, NL, false>(xv, a3v, a2v, a1p, acc);

    #pragma unroll
    for (int g = 0; g < GG; g++)
        if (g < nvalid) atomicAdd(&out[(size_t)na[g] * CC + c], acc[g]);
}

extern "C" void kernel_launch(void* const* d_in, const int* in_sizes, int n_in,
                              void* d_out, int out_size, void* d_ws, size_t ws_size,
                              hipStream_t stream) {
    const float* x   = (const float*)d_in[0];
    const int* types = (const int*)d_in[1];
    const float* U3  = (const float*)d_in[2];
    const float* U2  = (const float*)d_in[3];
    const float* U1  = (const float*)d_in[4];
    const float* W3  = (const float*)d_in[5];
    const float* W2  = (const float*)d_in[6];
    const float* W1  = (const float*)d_in[7];
    float* out = (float*)d_out;
    int N = in_sizes[1];  // atom count (2048)

    int ngmax = (N + GG - 1) / GG + EE;  // strict upper bound on group count

    float* ws   = (float*)d_ws;
    float* U3s  = ws;                           // NTRI*P3
    float* U2s  = U3s + NTRI * P3;              // NPAIR*P2
    float* A3   = U2s + NPAIR * P2;             // EE*NTRI*CC (interleaved x4)
    float* A2   = A3 + (size_t)EE * NTRI * CC;  // EE*NPAIR*CC (interleaved x2)
    float* A1   = A2 + (size_t)EE * NPAIR * CC; // EE*NL*CC
    int* buckets = (int*)(A1 + (size_t)EE * NL * CC);  // EE*N
    int* groups  = buckets + (size_t)EE * N;    // ngmax*8
    int* ngroups = groups + (size_t)ngmax * 8;

    hipMemsetAsync(out, 0, (size_t)out_size * sizeof(float), stream);

    int symThreads = NTRI * P3 + NPAIR * P2;
    hipLaunchKernelGGL(k_symU, dim3((symThreads + 255) / 256), dim3(256), 0, stream,
                       U3, U2, U3s, U2s);
    hipLaunchKernelGGL(k_buildA, dim3(EE * (NTRI / 4) + EE * (NPAIR / 2) + EE), dim3(CC), 0,
                       stream, U3s, U2s, U1, W3, W2, W1, A3, A2, A1);
    hipLaunchKernelGGL(k_prep, dim3(1), dim3(256), 0, stream,
                       types, buckets, groups, ngroups, N);
    hipLaunchKernelGGL(k_main, dim3(ngmax, 2), dim3(CC), 0, stream,
                       x, A3, A2, A1, groups, ngroups, out);
}

// Round 8
// 108.668 us; speedup vs baseline: 2.1157x; 1.0699x over previous
//
#include <hip/hip_runtime.h>

// MACE symmetric contraction (corr-3), N=2048, NL=16, C=128, E=10, P3=23, P2=4, P1=1.
// out[n,c] = sum_{a<=b<=i} A3[t,tri,c] x_a x_b x_i + sum_{a<=b} A2[t,pr,c] x_a x_b
//          + sum_a A1[t,a,c] x_a,  with A3 = U3sym @ W3[t] etc. (t = atom type).
// R9b: identical to R9 (bench infra failed twice; kernel audited clean).
//   axis 1 (non-k_main): fuse symU into the build kernel (LDS-local U sym) and
//     fold prep in as one extra block -> 5 dispatches become 2.
//   axis 2 (k_main, outside the body): 3-way a-split {0,4,8,16} (1566 blocks
//     ~6/CU, grid was occupancy-limiting at 4.1/CU) + XCD-chunked bijective
//     swizzle (each XCD's L2 holds ~1-2 types' A3 slice).
//   eval_nest body is byte-identical to the proven R0/R8 kernel.

constexpr int NL = 16;
constexpr int CC = 128;
constexpr int EE = 10;
constexpr int P3 = 23;
constexpr int P2 = 4;
constexpr int P1 = 1;
constexpr int NTRI = 816;   // C(18,3): a<=b<=i from 16
constexpr int NPAIR = 136;  // C(17,2): a<=b from 16
constexpr int GG = 4;       // atoms per group
constexpr int S1 = 4;       // nest split: a in [0,4) | [4,8) | [8,16)
constexpr int S2 = 8;

constexpr int pairsBefore(int a) {
    int s = 0;
    for (int x = 0; x < a; x++) s += NL - x;
    return s;
}
constexpr int trisBefore(int a) {
    int s = 0;
    for (int x = 0; x < a; x++) s += (NL - x) * (NL - x + 1) / 2;
    return s;
}
static_assert(trisBefore(S1) % 4 == 0, "tri split1 must be float4-aligned");
static_assert(pairsBefore(S1) % 2 == 0, "pair split1 must be float2-aligned");
static_assert(trisBefore(S2) % 4 == 0, "tri split2 must be float4-aligned");
static_assert(pairsBefore(S2) % 2 == 0, "pair split2 must be float2-aligned");

// ---------------- Fused precompute + bucketing ----------------
// Block roles: [0, NB3)            A3 build (4 tris, symU inline via LDS)
//              [NB3, NB3+NB2)      A2 build (2 pairs, symU2 inline via LDS)
//              [.., +EE)           A1 build (one type)
//              last block          atom bucketing/grouping
__global__ void k_pre(const float* __restrict__ U3, const float* __restrict__ U2,
                      const float* __restrict__ U1,
                      const float* __restrict__ W3, const float* __restrict__ W2,
                      const float* __restrict__ W1,
                      const int* __restrict__ types,
                      float* __restrict__ A3, float* __restrict__ A2,
                      float* __restrict__ A1,
                      int* __restrict__ buckets, int* __restrict__ groups,
                      int* __restrict__ ngroups, int N) {
    constexpr int NB3 = EE * (NTRI / 4);
    constexpr int NB2 = EE * (NPAIR / 2);
    __shared__ float u3l[4 * P3];   // A3 blocks: symmetrized U3 for 4 tris
    __shared__ float u2l[2 * P2];   // A2 blocks: symmetrized U2 for 2 pairs
    __shared__ int scnt[EE];        // prep block
    __shared__ int goff[EE + 1];    // prep block
    int b = blockIdx.x;
    int tid = threadIdx.x;

    if (b < NB3) {
        int t = b / (NTRI / 4), tri4 = b % (NTRI / 4);
        for (int idx = tid; idx < 4 * P3; idx += blockDim.x) {
            int lt = idx / P3, k = idx % P3;
            int tri = tri4 * 4 + lt;
            int rem = tri, a = 0;
            while (rem >= (NL - a) * (NL - a + 1) / 2) { rem -= (NL - a) * (NL - a + 1) / 2; a++; }
            int bb = a;
            while (rem >= NL - bb) { rem -= NL - bb; bb++; }
            int i = bb + rem;
            auto u = [&](int p, int q, int r) { return U3[((p * NL + q) * NL + r) * P3 + k]; };
            float s = u(a,bb,i) + u(a,i,bb) + u(bb,a,i) + u(bb,i,a) + u(i,a,bb) + u(i,bb,a);
            int m = (a == bb && bb == i) ? 6 : ((a == bb || bb == i) ? 2 : 1);
            u3l[idx] = s / (float)m;
        }
        __syncthreads();
        int c = tid;
        float4 sv = {0.f, 0.f, 0.f, 0.f};
        #pragma unroll
        for (int k = 0; k < P3; k++) {
            float w = W3[(t * P3 + k) * CC + c];
            sv.x += u3l[0 * P3 + k] * w;
            sv.y += u3l[1 * P3 + k] * w;
            sv.z += u3l[2 * P3 + k] * w;
            sv.w += u3l[3 * P3 + k] * w;
        }
        ((float4*)A3)[((size_t)t * (NTRI / 4) + tri4) * CC + c] = sv;
    } else if (b < NB3 + NB2) {
        int j = b - NB3;
        int t = j / (NPAIR / 2), pr2 = j % (NPAIR / 2);
        for (int idx = tid; idx < 2 * P2; idx += blockDim.x) {
            int lp = idx / P2, k = idx % P2;
            int pr = pr2 * 2 + lp;
            int rem = pr, a = 0;
            while (rem >= NL - a) { rem -= NL - a; a++; }
            int bb = a + rem;
            float s = U2[(a * NL + bb) * P2 + k];
            if (a != bb) s += U2[(bb * NL + a) * P2 + k];
            u2l[idx] = s;
        }
        __syncthreads();
        int c = tid;
        float2 sv = {0.f, 0.f};
        #pragma unroll
        for (int k = 0; k < P2; k++) {
            float w = W2[(t * P2 + k) * CC + c];
            sv.x += u2l[0 * P2 + k] * w;
            sv.y += u2l[1 * P2 + k] * w;
        }
        ((float2*)A2)[((size_t)t * (NPAIR / 2) + pr2) * CC + c] = sv;
    } else if (b < NB3 + NB2 + EE) {
        int t = b - NB3 - NB2;
        int c = tid;
        #pragma unroll
        for (int a = 0; a < NL; a++) {
            // P1 == 1: A1[t,a,c] = U1[a] * W1[t,0,c]
            A1[((size_t)t * NL + a) * CC + c] = U1[a * P1] * W1[(size_t)t * P1 * CC + c];
        }
    } else {
        // ---- bucketing / grouping (single block) ----
        if (tid < EE) scnt[tid] = 0;
        __syncthreads();
        for (int n = tid; n < N; n += blockDim.x) {
            int t = types[n];
            int pos = atomicAdd(&scnt[t], 1);
            buckets[t * N + pos] = n;
        }
        __syncthreads();
        if (tid == 0) {
            int off = 0;
            for (int t = 0; t < EE; t++) { goff[t] = off; off += (scnt[t] + GG - 1) / GG; }
            goff[EE] = off;
            *ngroups = off;
        }
        __syncthreads();
        for (int t = 0; t < EE; t++) {
            int cnt = scnt[t];
            int ng = (cnt + GG - 1) / GG;
            for (int g = tid; g < ng; g += blockDim.x) {
                int* gr = &groups[(goff[t] + g) * 8];
                int nv = cnt - g * GG; if (nv > GG) nv = GG;
                gr[0] = t;
                gr[5] = nv;
                for (int j = 0; j < GG; j++) {
                    int jj = j < nv ? j : nv - 1;
                    gr[1 + j] = buckets[t * N + g * GG + jj];
                }
            }
        }
    }
}

// ---------------- Main: evaluate cubic form per (group-slice, channel) -------
// R0/R8-proven body — DO NOT TOUCH: per tri, acc[g] += w3 * (p[g] * xv[g][i]).
template <int A0, int A1, bool LIN>
__device__ __forceinline__ void eval_nest(const float (&xv)[GG][NL],
                                          const float4* __restrict__ a3v,
                                          const float2* __restrict__ a2v,
                                          const float* __restrict__ a1p,
                                          float (&acc)[GG]) {
    if (LIN) {
        #pragma unroll
        for (int a = 0; a < NL; a++) {
            float w = a1p[a * CC];
            #pragma unroll
            for (int g = 0; g < GG; g++) acc[g] += w * xv[g][a];
        }
    }
    float4 w4 = {0.f, 0.f, 0.f, 0.f};
    float2 wp = {0.f, 0.f};
    int tri = trisBefore(A0), pr = pairsBefore(A0);
    #pragma unroll
    for (int a = A0; a < A1; a++) {
        #pragma unroll
        for (int b = a; b < NL; b++) {
            float p[GG];
            #pragma unroll
            for (int g = 0; g < GG; g++) p[g] = xv[g][a] * xv[g][b];
            if ((pr & 1) == 0) wp = a2v[(size_t)(pr >> 1) * CC];
            float w2 = ((pr & 1) == 0) ? wp.x : wp.y;
            pr++;
            #pragma unroll
            for (int g = 0; g < GG; g++) acc[g] += w2 * p[g];
            #pragma unroll
            for (int i = b; i < NL; i++) {
                if ((tri & 3) == 0) w4 = a3v[(size_t)(tri >> 2) * CC];
                int r = tri & 3;
                float w3 = (r == 0) ? w4.x : (r == 1) ? w4.y : (r == 2) ? w4.z : w4.w;
                tri++;
                #pragma unroll
                for (int g = 0; g < GG; g++) acc[g] += w3 * (p[g] * xv[g][i]);
            }
        }
    }
}

__global__ __launch_bounds__(CC, 3) void k_main(const float* __restrict__ x,
                                                const float* __restrict__ A3,
                                                const float* __restrict__ A2,
                                                const float* __restrict__ A1,
                                                const int* __restrict__ groups,
                                                const int* __restrict__ ngroups,
                                                float* __restrict__ out) {
    // XCD-chunked bijective swizzle (m204 form): physical blocks round-robin
    // XCDs; give each XCD a contiguous LOGICAL group chunk so its L2 holds the
    // A3 slices of only ~1-2 atom types (groups are type-sorted).
    int pb = blockIdx.x;
    int nb = gridDim.x;
    int q = nb >> 3, r = nb & 7;
    int xcd = pb & 7, sub = pb >> 3;
    int blk = (xcd < r ? xcd * (q + 1) : r * (q + 1) + (xcd - r) * q) + sub;
    if (blk >= *ngroups) return;
    const int* gr = groups + blk * 8;
    int t = gr[0];
    int nvalid = gr[5];
    int c = threadIdx.x;

    int na[GG];
    #pragma unroll
    for (int g = 0; g < GG; g++) na[g] = gr[1 + g];

    float xv[GG][NL];
    #pragma unroll
    for (int g = 0; g < GG; g++)
        #pragma unroll
        for (int i = 0; i < NL; i++)
            xv[g][i] = x[((size_t)na[g] * NL + i) * CC + c];

    const float4* a3v = (const float4*)A3 + (size_t)t * (NTRI / 4) * CC + c;
    const float2* a2v = (const float2*)A2 + (size_t)t * (NPAIR / 2) * CC + c;
    const float* a1p = A1 + (size_t)t * NL * CC + c;

    float acc[GG] = {0.f, 0.f, 0.f, 0.f};
    if (blockIdx.y == 0)
        eval_nest<0, S1, true>(xv, a3v, a2v, a1p, acc);
    else if (blockIdx.y == 1)
        eval_nest<S1, S2, false>(xv, a3v, a2v, a1p, acc);
    else
        eval_nest<S2, NL, false>(xv, a3v, a2v, a1p, acc);

    #pragma unroll
    for (int g = 0; g < GG; g++)
        if (g < nvalid) atomicAdd(&out[(size_t)na[g] * CC + c], acc[g]);
}

extern "C" void kernel_launch(void* const* d_in, const int* in_sizes, int n_in,
                              void* d_out, int out_size, void* d_ws, size_t ws_size,
                              hipStream_t stream) {
    const float* x   = (const float*)d_in[0];
    const int* types = (const int*)d_in[1];
    const float* U3  = (const float*)d_in[2];
    const float* U2  = (const float*)d_in[3];
    const float* U1  = (const float*)d_in[4];
    const float* W3  = (const float*)d_in[5];
    const float* W2  = (const float*)d_in[6];
    const float* W1  = (const float*)d_in[7];
    float* out = (float*)d_out;
    int N = in_sizes[1];  // atom count (2048)

    int ngmax = (N + GG - 1) / GG + EE;  // strict upper bound on group count

    float* ws   = (float*)d_ws;
    float* A3   = ws;                           // EE*NTRI*CC (interleaved x4)
    float* A2   = A3 + (size_t)EE * NTRI * CC;  // EE*NPAIR*CC (interleaved x2)
    float* A1   = A2 + (size_t)EE * NPAIR * CC; // EE*NL*CC
    int* buckets = (int*)(A1 + (size_t)EE * NL * CC);  // EE*N
    int* groups  = buckets + (size_t)EE * N;    // ngmax*8
    int* ngroups = groups + (size_t)ngmax * 8;

    hipMemsetAsync(out, 0, (size_t)out_size * sizeof(float), stream);

    constexpr int NB3 = EE * (NTRI / 4);
    constexpr int NB2 = EE * (NPAIR / 2);
    hipLaunchKernelGGL(k_pre, dim3(NB3 + NB2 + EE + 1), dim3(CC), 0, stream,
                       U3, U2, U1, W3, W2, W1, types,
                       A3, A2, A1, buckets, groups, ngroups, N);
    hipLaunchKernelGGL(k_main, dim3(ngmax, 3), dim3(CC), 0, stream,
                       x, A3, A2, A1, groups, ngroups, out);
}